// Round 6
// baseline (118.135 us; speedup 1.0000x reference)
//
#include <hip/hip_runtime.h>
#include <hip/hip_bf16.h>

typedef unsigned short u16;
typedef unsigned int u32;
typedef __attribute__((ext_vector_type(2))) unsigned int u32x2;
typedef __attribute__((ext_vector_type(4))) unsigned int u32x4;
typedef __attribute__((ext_vector_type(8))) short bf16x8;    // 8 bf16 (4 VGPRs)
typedef __attribute__((ext_vector_type(16))) float f32x16;   // 32x32 MFMA C/D

__device__ __forceinline__ u32 cvtpk(float lo, float hi) {   // v_cvt_pk_bf16_f32
    __hip_bfloat162 h = __float22bfloat162_rn(make_float2(lo, hi));
    u32 r;
    __builtin_memcpy(&r, &h, 4);   // bit_cast rejects non-trivially-copyable bf162
    return r;
}

#define NROW 4096
#define CK 64
#define CV 128
#define VS_OFF 4096   // u16 idx: V^T tile [128 v][64 j] bf16 (16KB); K tile at 0 (8KB)
#define SW(R, o) ((((R) << 7) + (o)) ^ (((R) & 7) << 4))   // 128B-stride XOR swizzle

// 512 blocks x 256 thr (4 waves). batch = bid&7 (XCD L2 affinity);
// grp = bid>>3: m = grp<32 ? 63-grp : grp-32  (heavy blocks dispatched first;
// resident pair (bid, bid+256) sums to constant work). Block owns ADJACENT
// q-tiles {2m, 2m+1} (32 rows each): wave w -> tile T=2m+(w>>1), j-parity
// share h=w&1 (slices jS = 2*tt+h, tt = staged 64-row KV tile index).
// Dense packing: all 4 waves active until the final 1-2 rounds.
__global__ __launch_bounds__(256, 2) void attn_k(const float* __restrict__ Qg,
                                                 const float* __restrict__ Kg,
                                                 const float* __restrict__ Vg,
                                                 float* __restrict__ O) {
    __shared__ __align__(16) u16 smem[12288];   // 24KB; epilogue overlays 8.3KB

    int bid = blockIdx.x;
    int bb  = bid & 7;
    int grp = bid >> 3;                          // 0..63
    int m   = (grp < 32) ? (63 - grp) : (grp - 32);
    int t   = threadIdx.x;
    int w   = t >> 6;
    int lane = t & 63;
    int ql = lane & 31, hl = lane >> 5;
    int p  = w >> 1;                             // q-tile within block
    int h  = w & 1;                              // j-parity share
    int T  = 2 * m + p;
    int qbw = T << 5;
    int NTb = m + 1;                             // staged 64-row KV tiles

    const float* Qp = Qg + (size_t)bb * NROW * CK;
    const float* Kp = Kg + (size_t)bb * NROW * CK;
    const float* Vp = Vg + (size_t)bb * NROW * CV;

    const float qscale = 0.125f * 1.44269504088896f;   // 1/sqrt(64) * log2(e)

    // Q B-fragments (col=q=ql, k = kc*16 + hl*8 + e), scale folded
    bf16x8 qf[4];
#pragma unroll
    for (int kc = 0; kc < 4; kc++) {
        const float* qp = Qp + (size_t)(qbw + ql) * CK + kc * 16 + hl * 8;
        float4 a = *(const float4*)qp;
        float4 b = *(const float4*)(qp + 4);
        u32x4 qq;
        qq[0] = cvtpk(a.x * qscale, a.y * qscale);
        qq[1] = cvtpk(a.z * qscale, a.w * qscale);
        qq[2] = cvtpk(b.x * qscale, b.y * qscale);
        qq[3] = cvtpk(b.z * qscale, b.w * qscale);
        qf[kc] = __builtin_bit_cast(bf16x8, qq);
    }

    f32x16 acc[4];
#pragma unroll
    for (int vs = 0; vs < 4; vs++)
#pragma unroll
        for (int r = 0; r < 16; r++) acc[vs][r] = 0.f;
    float l = 0.f;

    // staging (256 thr): K row jK=t>>2, cols oc*16..+15 (4 float4 -> 2 x16B LDS)
    //                    V rows quad*4+0..3, v-cols c8*8..+7 (8 float4 -> 8 x8B LDS^T)
    int jK = t >> 2, oc = t & 3;
    int quad = t & 15, c8 = t >> 4;
    const float* kSrc = Kp + (size_t)jK * CK + oc * 16;
    const float* vSrc = Vp + (size_t)(quad * 4) * CV + c8 * 8;

    float4 ka0, ka1, ka2, ka3, va0, va1, va2, va3, vb0, vb1, vb2, vb3;
    ka0 = *(const float4*)(kSrc);     ka1 = *(const float4*)(kSrc + 4);
    ka2 = *(const float4*)(kSrc + 8); ka3 = *(const float4*)(kSrc + 12);
    va0 = *(const float4*)(vSrc);          vb0 = *(const float4*)(vSrc + 4);
    va1 = *(const float4*)(vSrc + CV);     vb1 = *(const float4*)(vSrc + CV + 4);
    va2 = *(const float4*)(vSrc + 2 * CV); vb2 = *(const float4*)(vSrc + 2 * CV + 4);
    va3 = *(const float4*)(vSrc + 3 * CV); vb3 = *(const float4*)(vSrc + 3 * CV + 4);

    for (int tt = 0; tt < NTb; ++tt) {
        __syncthreads();   // WAR
        {   // ---- store prefetched tile (fp32 regs -> bf16 LDS, swizzled) ----
            u32x4 kk0, kk1;
            kk0[0] = cvtpk(ka0.x, ka0.y); kk0[1] = cvtpk(ka0.z, ka0.w);
            kk0[2] = cvtpk(ka1.x, ka1.y); kk0[3] = cvtpk(ka1.z, ka1.w);
            kk1[0] = cvtpk(ka2.x, ka2.y); kk1[1] = cvtpk(ka2.z, ka2.w);
            kk1[2] = cvtpk(ka3.x, ka3.y); kk1[3] = cvtpk(ka3.z, ka3.w);
            *(u32x4*)&smem[SW(jK, oc * 32) >> 1]      = kk0;
            *(u32x4*)&smem[SW(jK, oc * 32 + 16) >> 1] = kk1;
#pragma unroll
            for (int i = 0; i < 4; i++) {
                int cv = c8 * 8 + i;
                u32x2 vv; vv[0] = cvtpk(va0[i], va1[i]); vv[1] = cvtpk(va2[i], va3[i]);
                *(u32x2*)&smem[VS_OFF + (SW(cv, quad * 8) >> 1)] = vv;
            }
#pragma unroll
            for (int i = 0; i < 4; i++) {
                int cv = c8 * 8 + 4 + i;
                u32x2 vv; vv[0] = cvtpk(vb0[i], vb1[i]); vv[1] = cvtpk(vb2[i], vb3[i]);
                *(u32x2*)&smem[VS_OFF + (SW(cv, quad * 8) >> 1)] = vv;
            }
        }
        __syncthreads();   // RAW
        {   // ---- prefetch next tile into regs ----
            int nt = (tt + 1 < NTb) ? (tt + 1) : tt;
            const float* kp = kSrc + (size_t)nt * 4096;
            const float* vp = vSrc + (size_t)nt * 8192;
            ka0 = *(const float4*)(kp);     ka1 = *(const float4*)(kp + 4);
            ka2 = *(const float4*)(kp + 8); ka3 = *(const float4*)(kp + 12);
            va0 = *(const float4*)(vp);          vb0 = *(const float4*)(vp + 4);
            va1 = *(const float4*)(vp + CV);     vb1 = *(const float4*)(vp + CV + 4);
            va2 = *(const float4*)(vp + 2 * CV); vb2 = *(const float4*)(vp + 2 * CV + 4);
            va3 = *(const float4*)(vp + 3 * CV); vb3 = *(const float4*)(vp + 3 * CV + 4);
        }

        int jS = 2 * tt + h;               // this wave's 32-j slice index
        if (jS > T) continue;              // above diagonal (no barriers skipped)

        // ---- QK^T swapped (S = K x Q): 2 independent 2-chains ----
        bf16x8 kf0 = *(const bf16x8*)&smem[SW(h * 32 + ql, 0 * 32 + hl * 16) >> 1];
        bf16x8 kf1 = *(const bf16x8*)&smem[SW(h * 32 + ql, 1 * 32 + hl * 16) >> 1];
        bf16x8 kf2 = *(const bf16x8*)&smem[SW(h * 32 + ql, 2 * 32 + hl * 16) >> 1];
        bf16x8 kf3 = *(const bf16x8*)&smem[SW(h * 32 + ql, 3 * 32 + hl * 16) >> 1];
        f32x16 Sa, Sb;
#pragma unroll
        for (int r = 0; r < 16; r++) { Sa[r] = 0.f; Sb[r] = 0.f; }
        __builtin_amdgcn_s_setprio(1);
        Sa = __builtin_amdgcn_mfma_f32_32x32x16_bf16(kf0, qf[0], Sa, 0, 0, 0);
        Sb = __builtin_amdgcn_mfma_f32_32x32x16_bf16(kf2, qf[2], Sb, 0, 0, 0);
        Sa = __builtin_amdgcn_mfma_f32_32x32x16_bf16(kf1, qf[1], Sa, 0, 0, 0);
        Sb = __builtin_amdgcn_mfma_f32_32x32x16_bf16(kf3, qf[3], Sb, 0, 0, 0);
        __builtin_amdgcn_s_setprio(0);

        // ---- P = exp2(S), strict-causal mask on the diagonal slice ----
        float P[16];
        bool diag = (jS == T);
#pragma unroll
        for (int r = 0; r < 16; r++) {
            float pr = __builtin_exp2f(Sa[r] + Sb[r]);
            if (diag) {
                int jl = (r & 3) + 8 * (r >> 2) + 4 * hl;
                pr = (jl >= ql) ? 0.f : pr;
            }
            P[r] = pr;
        }
        {
            float s0 = (P[0] + P[1]) + (P[2] + P[3]);
            float s1 = (P[4] + P[5]) + (P[6] + P[7]);
            float s2 = (P[8] + P[9]) + (P[10] + P[11]);
            float s3 = (P[12] + P[13]) + (P[14] + P[15]);
            l += (s0 + s1) + (s2 + s3);
        }

        // ---- P -> PV A-fragments: 8 cvt_pk + 4 batched shfl + 8 selects ----
        u32 A0 = cvtpk(P[0], P[1]),   B0 = cvtpk(P[2], P[3]);
        u32 A1 = cvtpk(P[4], P[5]),   B1 = cvtpk(P[6], P[7]);
        u32 A2 = cvtpk(P[8], P[9]),   B2 = cvtpk(P[10], P[11]);
        u32 A3 = cvtpk(P[12], P[13]), B3 = cvtpk(P[14], P[15]);
        u32 s1 = hl ? A0 : A1, s2 = hl ? B0 : B1;
        u32 s3 = hl ? A2 : A3, s4 = hl ? B2 : B3;
        u32 r1 = (u32)__shfl_xor((int)s1, 32);
        u32 r2 = (u32)__shfl_xor((int)s2, 32);
        u32 r3 = (u32)__shfl_xor((int)s3, 32);
        u32 r4 = (u32)__shfl_xor((int)s4, 32);

        // ---- V fragments (issued while shfls are in flight) ----
        bf16x8 vf0[4], vf1[4];
#pragma unroll
        for (int vs = 0; vs < 4; vs++) {
            vf0[vs] = *(const bf16x8*)&smem[VS_OFF + (SW(vs * 32 + ql, h * 64 + hl * 16) >> 1)];
            vf1[vs] = *(const bf16x8*)&smem[VS_OFF + (SW(vs * 32 + ql, h * 64 + 32 + hl * 16) >> 1)];
        }

        u32x4 w0, w1;
        w0[0] = hl ? r1 : A0; w0[1] = hl ? r2 : B0;
        w0[2] = hl ? A1 : r1; w0[3] = hl ? B1 : r2;
        w1[0] = hl ? r3 : A2; w1[1] = hl ? r4 : B2;
        w1[2] = hl ? A3 : r3; w1[3] = hl ? B3 : r4;
        bf16x8 pa0 = __builtin_bit_cast(bf16x8, w0);
        bf16x8 pa1 = __builtin_bit_cast(bf16x8, w1);

        // ---- PV: 4 independent chains of 2 ----
        __builtin_amdgcn_s_setprio(1);
#pragma unroll
        for (int vs = 0; vs < 4; vs++)
            acc[vs] = __builtin_amdgcn_mfma_f32_32x32x16_bf16(pa0, vf0[vs], acc[vs], 0, 0, 0);
#pragma unroll
        for (int vs = 0; vs < 4; vs++)
            acc[vs] = __builtin_amdgcn_mfma_f32_32x32x16_bf16(pa1, vf1[vs], acc[vs], 0, 0, 0);
        __builtin_amdgcn_s_setprio(0);
    }

    // ---- pair combine (pure add: fixed shift) + epilogue ----
    __syncthreads();
    float* cm = (float*)smem;              // 2 pairs x 1024 f32 per vs-chunk
    float* lA = (float*)smem + 2048;       // 2 x 32 f32
    float lsum = l + __shfl_xor(l, 32);
    float inv_r[16];
    float* Og = O + ((size_t)bb * NROW + qbw) * CV;
#pragma unroll
    for (int vs = 0; vs < 4; vs++) {
        if (h == 0) {
            if (vs == 0 && lane < 32) lA[p * 32 + lane] = lsum;
#pragma unroll
            for (int rc = 0; rc < 4; rc++) {
                float4 v4 = make_float4(acc[vs][rc * 4 + 0], acc[vs][rc * 4 + 1],
                                        acc[vs][rc * 4 + 2], acc[vs][rc * 4 + 3]);
                *(float4*)&cm[p * 1024 + rc * 256 + lane * 4] = v4;
            }
        }
        __syncthreads();
        if (h == 1) {
            if (vs == 0) {
                float ltot = lsum + lA[p * 32 + ql];
                float inv = (qbw + ql == 0) ? 0.f : 1.f / ltot;   // global row 0 -> 0
#pragma unroll
                for (int r = 0; r < 16; r++) {
                    int qi = (r & 3) + 8 * (r >> 2) + 4 * hl;
                    inv_r[r] = __shfl(inv, qi);
                }
            }
#pragma unroll
            for (int rc = 0; rc < 4; rc++) {
                float4 v4 = *(const float4*)&cm[p * 1024 + rc * 256 + lane * 4];
                acc[vs][rc * 4 + 0] += v4.x;
                acc[vs][rc * 4 + 1] += v4.y;
                acc[vs][rc * 4 + 2] += v4.z;
                acc[vs][rc * 4 + 3] += v4.w;
            }
#pragma unroll
            for (int r = 0; r < 16; r++) {
                int qi = (r & 3) + 8 * (r >> 2) + 4 * hl;
                Og[(size_t)qi * CV + vs * 32 + ql] = acc[vs][r] * inv_r[r];
            }
        }
        __syncthreads();
    }
}

// ---------------------------------------------------------------------------
extern "C" void kernel_launch(void* const* d_in, const int* in_sizes, int n_in,
                              void* d_out, int out_size, void* d_ws, size_t ws_size,
                              hipStream_t stream) {
    const float* Q = (const float*)d_in[0];
    const float* K = (const float*)d_in[1];
    const float* V = (const float*)d_in[2];
    float* out = (float*)d_out;
    hipLaunchKernelGGL(attn_k, dim3(512), dim3(256), 0, stream, Q, K, V, out);
}